// Round 1
// baseline (261.868 us; speedup 1.0000x reference)
//
#include <hip/hip_runtime.h>
#include <math.h>

#define D100 100
#define NE 50000
#define BATCH 16
#define EPS_F 1e-5f

// ---------------------------------------------------------------------------
// K1: Wm[t][b][e][f] = sum_k R2[r_idx[b]][k] * W_t[k][e][f]
// grid (40, 2), block 256
__global__ void k1_wm(const float* __restrict__ W_re, const float* __restrict__ W_im,
                      const float* __restrict__ R2, const int* __restrict__ r_idx,
                      float* __restrict__ Wm) {
  const int t = blockIdx.y;
  const float* W = t ? W_im : W_re;
  int ef = blockIdx.x * 256 + threadIdx.x;
  if (ef >= 10000) return;
  int ridx[16];
#pragma unroll
  for (int b = 0; b < 16; b++) ridx[b] = r_idx[b];
  float acc[16];
#pragma unroll
  for (int b = 0; b < 16; b++) acc[b] = 0.f;
  for (int k = 0; k < 100; k++) {
    float w = W[k * 10000 + ef];
#pragma unroll
    for (int b = 0; b < 16; b++) acc[b] = fmaf(R2[ridx[b] * 100 + k], w, acc[b]);
  }
  float* o = Wm + t * 160000 + ef;
#pragma unroll
  for (int b = 0; b < 16; b++) o[b * 10000] = acc[b];
}

// ---------------------------------------------------------------------------
// K2: block-partial Gram G = E^T E (128-padded, 8x8 register tiles) + colsums
// grid (NB, 2), block 256
__global__ __launch_bounds__(256) void k2_gram(const float* __restrict__ E_a,
                                               const float* __restrict__ E_b,
                                               float* __restrict__ Gp,
                                               float* __restrict__ CSp,
                                               int NB, int RPB) {
  const int t = blockIdx.y;
  const float* E = t ? E_b : E_a;
  const float4* E4 = (const float4*)E;
  __shared__ float sm[32][128];
  const int tid = threadIdx.x;
  const int bx = blockIdx.x;
  int r0 = bx * RPB;
  int rend = min(r0 + RPB, NE);

  // zero the pad columns 100..127 once (float4 staging only touches cols 0..99)
  for (int i = tid; i < 32 * 28; i += 256) {
    int r = i / 28;
    sm[r][100 + (i - r * 28)] = 0.f;
  }

  float acc[8][8];
#pragma unroll
  for (int i = 0; i < 8; i++)
#pragma unroll
    for (int j = 0; j < 8; j++) acc[i][j] = 0.f;
  float cs = 0.f;
  const int ty = tid >> 4, tx = tid & 15;

  for (int base = r0; base < rend; base += 32) {
    int cnt = min(32, rend - base);
    __syncthreads();
    for (int i = tid; i < 800; i += 256) {
      int r = i / 25, c4 = i - r * 25;
      float4 v = make_float4(0.f, 0.f, 0.f, 0.f);
      if (r < cnt) v = E4[(base + r) * 25 + c4];
      *(float4*)&sm[r][c4 * 4] = v;
    }
    __syncthreads();
#pragma unroll 2
    for (int r = 0; r < 32; r++) {
      float4 a0 = *(const float4*)&sm[r][ty * 8];
      float4 a1 = *(const float4*)&sm[r][ty * 8 + 4];
      float4 b0 = *(const float4*)&sm[r][tx * 8];
      float4 b1 = *(const float4*)&sm[r][tx * 8 + 4];
      float av[8] = {a0.x, a0.y, a0.z, a0.w, a1.x, a1.y, a1.z, a1.w};
      float bv[8] = {b0.x, b0.y, b0.z, b0.w, b1.x, b1.y, b1.z, b1.w};
#pragma unroll
      for (int i = 0; i < 8; i++)
#pragma unroll
        for (int j = 0; j < 8; j++) acc[i][j] = fmaf(av[i], bv[j], acc[i][j]);
    }
    if (tid < 100) {
#pragma unroll 4
      for (int r = 0; r < 32; r++) cs += sm[r][tid];
    }
  }

  float* gp = Gp + (t * NB + bx) * 10000;
#pragma unroll
  for (int i = 0; i < 8; i++) {
    int e = ty * 8 + i;
    if (e < 100) {
#pragma unroll
      for (int j = 0; j < 8; j++) {
        int ep = tx * 8 + j;
        if (ep < 100) gp[e * 100 + ep] = acc[i][j];
      }
    }
  }
  if (tid < 100) CSp[(t * NB + bx) * 100 + tid] = cs;
}

// ---------------------------------------------------------------------------
// K3: reduce Gram partials and colsum partials.  grid (80), block 256
__global__ void k3_reduce(const float* __restrict__ Gp, const float* __restrict__ CSp,
                          float* __restrict__ G, float* __restrict__ CS, int NB) {
  int bid = blockIdx.x;
  int t = bid / 40, chunk = bid - t * 40;
  int idx = chunk * 256 + threadIdx.x;
  if (idx < 10000) {
    float s = 0.f;
    const float* p = Gp + t * NB * 10000 + idx;
    for (int nb = 0; nb < NB; nb++) s += p[nb * 10000];
    G[t * 10000 + idx] = s;
  }
  if (chunk == 0 && threadIdx.x < 100) {
    float s = 0.f;
    const float* p = CSp + t * NB * 100 + threadIdx.x;
    for (int nb = 0; nb < NB; nb++) s += p[nb * 100];
    CS[t * 100 + threadIdx.x] = s;
  }
}

// ---------------------------------------------------------------------------
// K4: gather h, BN2 over batch, per-batch matvec with Wm -> traw
// grid (16), block 256
__global__ void k4_core1(const float* __restrict__ E_a, const float* __restrict__ E_b,
                         const int* __restrict__ h_idx, const float* __restrict__ Wm,
                         const float* __restrict__ g0r, const float* __restrict__ b0r,
                         const float* __restrict__ g0i, const float* __restrict__ b0i,
                         float* __restrict__ traw) {
  __shared__ float ha[1600], hb[1600], xa[100], xb[100];
  int tid = threadIdx.x, bo = blockIdx.x;
  for (int idx = tid; idx < 1600; idx += 256) {
    int bb = idx / 100, e = idx - bb * 100;
    int h = h_idx[bb];
    ha[idx] = E_a[h * 100 + e];
    hb[idx] = E_b[h * 100 + e];
  }
  __syncthreads();
  if (tid < 100) {
    float m = 0.f, s = 0.f;
#pragma unroll
    for (int b = 0; b < 16; b++) { float v = ha[b * 100 + tid]; m += v; s += v * v; }
    m *= (1.f / 16.f);
    float var = s * (1.f / 16.f) - m * m;
    xa[tid] = (ha[bo * 100 + tid] - m) * rsqrtf(var + EPS_F) * g0r[tid] + b0r[tid];
    m = 0.f; s = 0.f;
#pragma unroll
    for (int b = 0; b < 16; b++) { float v = hb[b * 100 + tid]; m += v; s += v * v; }
    m *= (1.f / 16.f);
    var = s * (1.f / 16.f) - m * m;
    xb[tid] = (hb[bo * 100 + tid] - m) * rsqrtf(var + EPS_F) * g0i[tid] + b0i[tid];
  }
  __syncthreads();
  if (tid < 100) {
    float sa = 0.f, sb = 0.f;
    const float* wa = Wm + bo * 10000 + tid;
    const float* wb = Wm + 160000 + bo * 10000 + tid;
    for (int e = 0; e < 100; e++) {
      sa = fmaf(xa[e], wa[e * 100], sa);
      sb = fmaf(xb[e], wb[e * 100], sb);
    }
    traw[bo * 100 + tid] = sa;
    traw[1600 + bo * 100 + tid] = sb;
  }
}

// ---------------------------------------------------------------------------
// K5: BN2 over batch of traw, then Mobius transform -> t0,t1.  grid(1), block 256
__global__ void k5_core2(const float* __restrict__ traw,
                         const float* __restrict__ R_re, const float* __restrict__ R_im,
                         const int* __restrict__ r_idx,
                         const float* __restrict__ g1r, const float* __restrict__ b1r,
                         const float* __restrict__ g1i, const float* __restrict__ b1i,
                         float* __restrict__ t01) {
  __shared__ float ta[1600], tb[1600], sca[100], sha[100], scb[100], shb[100];
  int tid = threadIdx.x;
  for (int i = tid; i < 1600; i += 256) { ta[i] = traw[i]; tb[i] = traw[1600 + i]; }
  __syncthreads();
  if (tid < 100) {
    float m = 0.f, s = 0.f;
#pragma unroll
    for (int b = 0; b < 16; b++) { float v = ta[b * 100 + tid]; m += v; s += v * v; }
    m *= (1.f / 16.f);
    float var = s * (1.f / 16.f) - m * m;
    float sc = rsqrtf(var + EPS_F) * g1r[tid];
    sca[tid] = sc; sha[tid] = b1r[tid] - m * sc;
    m = 0.f; s = 0.f;
#pragma unroll
    for (int b = 0; b < 16; b++) { float v = tb[b * 100 + tid]; m += v; s += v * v; }
    m *= (1.f / 16.f);
    var = s * (1.f / 16.f) - m * m;
    sc = rsqrtf(var + EPS_F) * g1i[tid];
    scb[tid] = sc; shb[tid] = b1i[tid] - m * sc;
  }
  __syncthreads();
  for (int idx = tid; idx < 1600; idx += 256) {
    int b = idx / 100, f = idx - b * 100;
    float va = ta[idx] * sca[f] + sha[f];
    float vb = tb[idx] * scb[f] + shb[f];
    int base = r_idx[b] * 400 + f;
    float ra0 = R_re[base],       ra1 = R_im[base];
    float rb0 = R_re[base + 100], rb1 = R_im[base + 100];
    float rc0 = R_re[base + 200], rc1 = R_im[base + 200];
    float rd0 = R_re[base + 300], rd1 = R_im[base + 300];
    float top0 = va * ra0 - vb * ra1 + rb0;
    float top1 = va * ra1 + vb * ra0 + rb1;
    float bot0 = va * rc0 - vb * rc1 + rd0;
    float bot1 = va * rc1 + vb * rc0 + rd1;
    float den = bot0 * bot0 + bot1 * bot1;
    t01[idx]        = (top0 * bot0 + top1 * bot1) / den;
    t01[1600 + idx] = (top1 * bot0 - top0 * bot1) / den;
  }
}

// ---------------------------------------------------------------------------
// K6: P[t][b][ep][f] = (sum_e Wm[t][b][e][f] * G[t][e][ep]) * Wm[t][b][ep][f]
// grid (40, 16, 2), block 256
__global__ void k6_v(const float* __restrict__ Wm, const float* __restrict__ G,
                     float* __restrict__ P) {
  int t = blockIdx.z, b = blockIdx.y;
  int ef = blockIdx.x * 256 + threadIdx.x;
  if (ef >= 10000) return;
  int ep = ef / 100, f = ef - ep * 100;
  const float* Wmt = Wm + t * 160000 + b * 10000;
  const float* Gt = G + t * 10000 + ep;
  float a = 0.f;
  for (int e = 0; e < 100; e++) a = fmaf(Wmt[e * 100 + f], Gt[e * 100], a);
  P[t * 160000 + b * 10000 + ef] = a * Wmt[ep * 100 + f];
}

// ---------------------------------------------------------------------------
// K7: per-f BN3 stats: sumsq = sum P, mean = sum Wm*colsum / (B*N); -> alpha,beta
// grid (100, 2), block 256
__global__ void k7_stats(const float* __restrict__ P, const float* __restrict__ Wm,
                         const float* __restrict__ CS,
                         const float* __restrict__ gEa, const float* __restrict__ bEa,
                         const float* __restrict__ gEb, const float* __restrict__ bEb,
                         float* __restrict__ alpha, float* __restrict__ beta) {
  int f = blockIdx.x, t = blockIdx.y, tid = threadIdx.x;
  __shared__ float r1[256], r2[256];
  float s1 = 0.f, s2 = 0.f;
  const float* Pp = P + t * 160000 + f;
  const float* Wp = Wm + t * 160000 + f;
  const float* csp = CS + t * 100;
  for (int p = tid; p < 1600; p += 256) {
    s1 += Pp[p * 100];
    int e = p - (p / 100) * 100;
    s2 += Wp[p * 100] * csp[e];
  }
  r1[tid] = s1; r2[tid] = s2;
  __syncthreads();
  for (int o = 128; o > 0; o >>= 1) {
    if (tid < o) { r1[tid] += r1[tid + o]; r2[tid] += r2[tid + o]; }
    __syncthreads();
  }
  if (tid == 0) {
    float mean = r2[0] * (1.f / 800000.f);
    float var = r1[0] * (1.f / 800000.f) - mean * mean;
    float g = t ? gEb[f] : gEa[f];
    float bb = t ? bEb[f] : bEa[f];
    float al = rsqrtf(var + EPS_F) * g;
    alpha[t * 100 + f] = al;
    beta[t * 100 + f] = bb - mean * al;
  }
}

// ---------------------------------------------------------------------------
// K8: u_a[b][e] = sum_f (t0*alpha_a)[f]*Wm_re[b][e][f]  (+ im analog), c[b]
// grid (16), block 128.  u layout: u[(t*100+e)*16 + b] for scalar loads in K9.
__global__ void k8_u(const float* __restrict__ t01, const float* __restrict__ alpha,
                     const float* __restrict__ beta, const float* __restrict__ Wm,
                     float* __restrict__ u, float* __restrict__ c) {
  int b = blockIdx.x, tid = threadIdx.x;
  __shared__ float w0[100], w1[100], pc[128];
  float p = 0.f;
  if (tid < 100) {
    float t0 = t01[b * 100 + tid], t1 = t01[1600 + b * 100 + tid];
    w0[tid] = t0 * alpha[tid];
    w1[tid] = t1 * alpha[100 + tid];
    p = t0 * beta[tid] + t1 * beta[100 + tid];
  }
  pc[tid] = (tid < 100) ? p : 0.f;
  __syncthreads();
  for (int o = 64; o > 0; o >>= 1) {
    if (tid < o) pc[tid] += pc[tid + o];
    __syncthreads();
  }
  if (tid == 0) c[b] = pc[0];
  if (tid < 100) {
    float sa = 0.f, sb = 0.f;
    const float* wa = Wm + b * 10000 + tid * 100;
    const float* wb = Wm + 160000 + b * 10000 + tid * 100;
    for (int f = 0; f < 100; f++) {
      sa = fmaf(w0[f], wa[f], sa);
      sb = fmaf(w1[f], wb[f], sb);
    }
    u[tid * 16 + b] = sa;
    u[(100 + tid) * 16 + b] = sb;
  }
}

// ---------------------------------------------------------------------------
// K9: score[b][n] = sigmoid(c[b] + u_a[b]·E_a[n] + u_b[b]·E_b[n])
// grid (196), block 256.  u reads are wave-uniform -> s_load.
__device__ __forceinline__ float f4get(const float4& v, int j) {
  switch (j) { case 0: return v.x; case 1: return v.y; case 2: return v.z; default: return v.w; }
}

__global__ __launch_bounds__(256) void k9_score(const float* __restrict__ E_a,
                                                const float* __restrict__ E_b,
                                                const float* __restrict__ u,
                                                const float* __restrict__ c,
                                                float* __restrict__ out) {
  int n = blockIdx.x * 256 + threadIdx.x;
  if (n >= NE) return;
  const float4* Ea4 = (const float4*)E_a;
  const float4* Eb4 = (const float4*)E_b;
  float acc[16];
#pragma unroll
  for (int b = 0; b < 16; b++) acc[b] = 0.f;
  for (int e4 = 0; e4 < 25; e4++) {
    float4 va = Ea4[n * 25 + e4];
    float4 vb = Eb4[n * 25 + e4];
    const float* ua = u + e4 * 64;
    const float* ub = u + 1600 + e4 * 64;
#pragma unroll
    for (int j = 0; j < 4; j++) {
      float fa = f4get(va, j);
      float fb = f4get(vb, j);
#pragma unroll
      for (int b = 0; b < 16; b++) {
        acc[b] = fmaf(ua[j * 16 + b], fa, acc[b]);
        acc[b] = fmaf(ub[j * 16 + b], fb, acc[b]);
      }
    }
  }
#pragma unroll
  for (int b = 0; b < 16; b++) {
    float x = acc[b] + c[b];
    out[b * NE + n] = 1.f / (1.f + expf(-x));
  }
}

// ---------------------------------------------------------------------------
extern "C" void kernel_launch(void* const* d_in, const int* in_sizes, int n_in,
                              void* d_out, int out_size, void* d_ws, size_t ws_size,
                              hipStream_t stream) {
  const int* h_idx = (const int*)d_in[0];
  const int* r_idx = (const int*)d_in[1];
  const float* E_a = (const float*)d_in[2];
  const float* E_b = (const float*)d_in[3];
  const float* R_re = (const float*)d_in[4];
  const float* R_im = (const float*)d_in[5];
  const float* R2 = (const float*)d_in[6];
  const float* W_re = (const float*)d_in[7];
  const float* W_im = (const float*)d_in[8];
  const float* g0r = (const float*)d_in[9];
  const float* b0r = (const float*)d_in[10];
  const float* g1r = (const float*)d_in[11];
  const float* b1r = (const float*)d_in[12];
  const float* g0i = (const float*)d_in[13];
  const float* b0i = (const float*)d_in[14];
  const float* g1i = (const float*)d_in[15];
  const float* b1i = (const float*)d_in[16];
  const float* gEa = (const float*)d_in[17];
  const float* bEa = (const float*)d_in[18];
  const float* gEb = (const float*)d_in[19];
  const float* bEb = (const float*)d_in[20];
  float* out = (float*)d_out;
  float* ws = (float*)d_ws;

  // fixed-size regions
  float* Wm = ws;                  // [2][16][10000]       320000
  float* P = Wm + 320000;          // [2][16][10000]       320000
  float* G = P + 320000;           // [2][10000]            20000
  float* CS = G + 20000;           // [2][100]                200
  float* traw = CS + 200;          // [2][16][100]           3200
  float* t01 = traw + 3200;        // [2][16][100]           3200
  float* alpha = t01 + 3200;       //                         200
  float* beta = alpha + 200;       //                         200
  float* u = beta + 200;           // [2][100][16]           3200
  float* c = u + 3200;             //                          16
  const long fixed = 670216;       // floats used above (incl. c)

  long avail = (long)(ws_size / 4);
  int NB = 120;
  long per_nb = 2 * 10000 + 2 * 100;  // Gp + CSp floats per block index
  long room = (avail - fixed - 64) / per_nb;
  if (room < NB) NB = (int)room;
  if (NB < 1) NB = 1;
  int RPB = (NE + NB - 1) / NB;

  float* Gp = c + 16;               // [2][NB][10000]
  float* CSp = Gp + (long)NB * 20000;  // [2][NB][100]

  hipLaunchKernelGGL(k1_wm, dim3(40, 2), dim3(256), 0, stream, W_re, W_im, R2, r_idx, Wm);
  hipLaunchKernelGGL(k2_gram, dim3(NB, 2), dim3(256), 0, stream, E_a, E_b, Gp, CSp, NB, RPB);
  hipLaunchKernelGGL(k3_reduce, dim3(80), dim3(256), 0, stream, Gp, CSp, G, CS, NB);
  hipLaunchKernelGGL(k4_core1, dim3(16), dim3(256), 0, stream, E_a, E_b, h_idx, Wm,
                     g0r, b0r, g0i, b0i, traw);
  hipLaunchKernelGGL(k5_core2, dim3(1), dim3(256), 0, stream, traw, R_re, R_im, r_idx,
                     g1r, b1r, g1i, b1i, t01);
  hipLaunchKernelGGL(k6_v, dim3(40, 16, 2), dim3(256), 0, stream, Wm, G, P);
  hipLaunchKernelGGL(k7_stats, dim3(100, 2), dim3(256), 0, stream, P, Wm, CS,
                     gEa, bEa, gEb, bEb, alpha, beta);
  hipLaunchKernelGGL(k8_u, dim3(16), dim3(128), 0, stream, t01, alpha, beta, Wm, u, c);
  hipLaunchKernelGGL(k9_score, dim3((NE + 255) / 256), dim3(256), 0, stream,
                     E_a, E_b, u, c, out);
}